// Round 11
// baseline (296.369 us; speedup 1.0000x reference)
//
#include <hip/hip_runtime.h>
#include <hip/hip_bf16.h>

using bf16 = __hip_bfloat16;

typedef __attribute__((ext_vector_type(8))) short short8;   // 8 x bf16 (4 VGPRs)
typedef __attribute__((ext_vector_type(4))) float f32x4;    // MFMA C/D

// MaskedMSA: B=4, S=2048, E=1024, HIDDEN=1024, HEADS=16
// Reference reshape mixes seq/hidden: with t=16u+r (u<128, r<16):
//   q[b,h,t,e] = qkv[b, 128h+u, 192r +   0 + e]
//   k[b,h,t,e] = qkv[b, 128h+u, 192r +  64 + e]
//   v[b,h,t,e] = qkv[b, 128h+u, 192r + 128 + e]
// Output: sa[b,h,t,e] -> out row 128h+u, col 64r+e. Causal mask on permuted t.
// Q columns of W_qkv/b_qkv are pre-scaled by scale*log2(e): exp2-domain scores.
//
// R5/R10 attn: 8-wave paired-chunk flash attn (attn < 85us, no longer top).
// R11: GEMM was the new top dispatch (85us, 606 TF, m97-structure ceiling:
// vmcnt(0) drain at every barrier). New gemm256: 256^2 tile, BK=64, 8 waves,
// double-buffered LDS with COUNTED vmcnt(8) across raw s_barriers (loads stay
// in flight; T4), XOR k-group swizzle for 2-way-free ds_read_b128 (T2, via
// pre-swizzled global source -- LDS dest stays linear per m104), setprio (T5),
// bijective XCD swizzle (T1).

#define CEXP 0.03188127742677263f  // (2*1024)^-0.5 * log2(e)

__device__ __forceinline__ unsigned short f2bf(float v) {
  bf16 h = __float2bfloat16(v);
  return *(unsigned short*)&h;
}
__device__ __forceinline__ unsigned int pack2bf(float a, float b) {
  return (unsigned int)f2bf(a) | ((unsigned int)f2bf(b) << 16);
}

// async global->LDS, 16B per lane; LDS dest = wave-uniform base + lane*16.
__device__ __forceinline__ void gload_lds16(const void* g, void* lds) {
  __builtin_amdgcn_global_load_lds(
      (const __attribute__((address_space(1))) unsigned int*)(g),
      (__attribute__((address_space(3))) unsigned int*)(lds), 16, 0, 0);
}

// ---- dtype detect: flag=1 if fp32 I/O, flag=0 if bf16 I/O.
__global__ void detect_kernel(const unsigned int* __restrict__ x, int* __restrict__ flag) {
  unsigned int w = x[threadIdx.x];
  unsigned int e = (w >> 7) & 0xFF;
  bool inband = (e >= 96 && e <= 133);
  unsigned long long m = __ballot(inband);
  if (threadIdx.x == 0) flag[0] = (__popcll(m) >= 48) ? 0 : 1;
}

// ---- convert n8*8 elements to bf16 (copy if already bf16)
__global__ __launch_bounds__(256) void convert_kernel(
    const void* __restrict__ src, bf16* __restrict__ dst, int n8,
    const int* __restrict__ flag) {
  int i = blockIdx.x * 256 + threadIdx.x;
  if (i >= n8) return;
  uint4 outv;
  if (*flag) {
    const float4* s = (const float4*)src + (size_t)i * 2;
    float4 a = s[0], b = s[1];
    outv.x = pack2bf(a.x, a.y);
    outv.y = pack2bf(a.z, a.w);
    outv.z = pack2bf(b.x, b.y);
    outv.w = pack2bf(b.z, b.w);
  } else {
    outv = ((const uint4*)src)[i];
  }
  ((uint4*)dst)[i] = outv;
}

// ---- b_qkv convert with Q-column pre-scale (cols with (i%192)<64)
__global__ void convert_bias_qkv(const void* __restrict__ src, bf16* __restrict__ dst,
                                 const int* __restrict__ flag) {
  int i = blockIdx.x * 256 + threadIdx.x;
  if (i >= 3072) return;
  float v = (*flag) ? ((const float*)src)[i]
                    : __bfloat162float(((const bf16*)src)[i]);
  if ((i % 192) < 64) v *= CEXP;
  dst[i] = __float2bfloat16(v);
}

// ---- transpose src[R][C] -> dst[C][R] (bf16 out); qscale: scale rows n with
// (n%192)<64 by CEXP (W_qkv Q columns -> exp2 domain).
__global__ __launch_bounds__(256) void transpose_bf16(
    const void* __restrict__ src, bf16* __restrict__ dst, int R, int Cc,
    const int* __restrict__ flag, int qscale) {
  __shared__ float tile[32][33];
  const int c0 = blockIdx.x * 32, r0 = blockIdx.y * 32;
  const int tx = threadIdx.x & 31, ty = threadIdx.x >> 5;  // 32 x 8
  const bool f32 = (*flag != 0);
#pragma unroll
  for (int it = 0; it < 4; ++it) {
    int r = ty + it * 8;
    float v;
    if (f32) v = ((const float*)src)[(size_t)(r0 + r) * Cc + c0 + tx];
    else     v = __bfloat162float(((const bf16*)src)[(size_t)(r0 + r) * Cc + c0 + tx]);
    tile[r][tx] = v;
  }
  __syncthreads();
#pragma unroll
  for (int it = 0; it < 4; ++it) {
    int r = ty + it * 8;   // dst row n = c0 + r
    float vv = tile[tx][r];
    if (qscale && (((c0 + r) % 192) < 64)) vv *= CEXP;
    dst[(size_t)(c0 + r) * R + r0 + tx] = __float2bfloat16(vv);
  }
}

// ---- V pre-transpose: Vtg[bh][d][key] (d<64, key<2048) from permuted qkv.
__global__ __launch_bounds__(256) void transpose_v(const bf16* __restrict__ qkv,
                                                   bf16* __restrict__ vtg)
{
  __shared__ short tile[64][72];
  const int bh = blockIdx.x;
  const int k0 = blockIdx.y * 64;
  const unsigned short* qk = (const unsigned short*)qkv + (size_t)bh * 393216;
  const int key = threadIdx.x & 63;
  const int dv = threadIdx.x >> 6;      // 0..3 -> d-range dv*16
  const int gk = k0 + key;
  const unsigned short* src =
      qk + (size_t)(gk >> 4) * 3072 + (gk & 15) * 192 + 128 + dv * 16;
  *(short8*)&tile[key][dv * 16] = *(const short8*)src;
  *(short8*)&tile[key][dv * 16 + 8] = *(const short8*)(src + 8);
  __syncthreads();
  const int d = threadIdx.x & 63;
  const int kv = threadIdx.x >> 6;      // 0..3 -> key-range kv*16
  unsigned short* dst =
      (unsigned short*)vtg + ((size_t)bh * 64 + d) * 2048 + k0 + kv * 16;
  short8 a, b;
#pragma unroll
  for (int j = 0; j < 8; ++j) {
    a[j] = tile[kv * 16 + j][d];
    b[j] = tile[kv * 16 + 8 + j][d];
  }
  *(short8*)dst = a;
  *(short8*)(dst + 8) = b;
}

// ---------------- MFMA GEMM, 256^2 tile, BK=64, 8 waves, counted-vmcnt dbuf.
// C[M,N] = A[M,K] @ BT[N,K]^T + bias. M%256==0, N%256==0, K%64==0.
// LDS layout per buffer: [row256][cg8][8 bf16], row stride 128B, LINEAR dest
// (gload_lds requirement). Swizzle: LDS[row][cg] holds global k-group
// cg^(row&7) -- pre-permuted at the SOURCE; reads apply the same XOR ->
// ds_read_b128 lands 2-way/bank (free). Main loop: stage(t+1) -> other buf,
// s_waitcnt vmcnt(8) (batch t complete; t+1 stays IN FLIGHT across barrier),
// raw s_barrier, compute 64 MFMA, raw s_barrier. vmcnt(0) only at final iter.
__global__ __launch_bounds__(512) void gemm256(
    const bf16* __restrict__ A, const bf16* __restrict__ BT,
    const bf16* __restrict__ bias, void* __restrict__ C,
    int M, int N, int K, int store_mode, const int* __restrict__ flag)
{
  __shared__ alignas(16) short As2[2][16384];  // [buf][row][cg][8] = 32 KB each
  __shared__ alignas(16) short Bs2[2][16384];
  const bool store_f32 = store_mode && (*flag != 0);
  const int tid = threadIdx.x;
  const int lane = tid & 63;
  const int w = tid >> 6;
  const int l15 = lane & 15, l4 = lane >> 4;
  const int wm2 = w >> 2, wn4 = w & 3;        // wave tile: rows wm2*128, cols wn4*64

  // ---- T1: bijective XCD remap (nwg % 8 == 0 for all our grids)
  const int nwg = gridDim.x * gridDim.y;
  const int orig = blockIdx.x + gridDim.x * blockIdx.y;
  const int qn = nwg >> 3;
  const int swz = (orig & 7) * qn + (orig >> 3);
  const int bx = swz % gridDim.x, by = swz / gridDim.x;
  const int m0 = by * 256, n0 = bx * 256;

  // ---- staging constants: thread covers row srow(+64q), k-group (tid&7),
  // source k pre-swizzled by ^(row&7) so linear LDS + XOR reads match.
  const int srow = tid >> 3;                  // 0..63
  const int koff = ((tid & 7) ^ (srow & 7)) << 3;
  const bf16* pa = A + (size_t)(m0 + srow) * K + koff;
  const bf16* pb = BT + (size_t)(n0 + srow) * K + koff;
  const int dst0 = tid * 8;                   // short offset, round 0

  const int rsw = l15 & 7;                    // read-side XOR term

  f32x4 acc[8][4] = {};
  const int nt = K >> 6;

  // prologue: stage step 0 -> buf 0 (8 gloads/thread)
#pragma unroll
  for (int q = 0; q < 4; ++q) {
    gload_lds16(pa + (size_t)(q * 64) * K, &As2[0][q * 4096 + dst0]);
    gload_lds16(pb + (size_t)(q * 64) * K, &Bs2[0][q * 4096 + dst0]);
  }

  for (int t = 0; t < nt; ++t) {
    const int c = t & 1;
    if (t + 1 < nt) {
      const int nb = c ^ 1;
      const bf16* sa_ = pa + (size_t)(t + 1) * 64;
      const bf16* sb_ = pb + (size_t)(t + 1) * 64;
#pragma unroll
      for (int q = 0; q < 4; ++q) {
        gload_lds16(sa_ + (size_t)(q * 64) * K, &As2[nb][q * 4096 + dst0]);
        gload_lds16(sb_ + (size_t)(q * 64) * K, &Bs2[nb][q * 4096 + dst0]);
      }
      asm volatile("s_waitcnt vmcnt(8)" ::: "memory");  // batch t landed; t+1 in flight
    } else {
      asm volatile("s_waitcnt vmcnt(0)" ::: "memory");  // final batch
    }
    __builtin_amdgcn_s_barrier();
    asm volatile("" ::: "memory");

#pragma unroll
    for (int s = 0; s < 2; ++s) {               // k-subtile of 32 within BK=64
      const int cgs = (((s << 2) | l4) ^ rsw) * 8;
      short8 af[8], bfr[4];
#pragma unroll
      for (int i = 0; i < 8; ++i)
        af[i] = *(const short8*)&As2[c][(wm2 * 128 + i * 16 + l15) * 64 + cgs];
#pragma unroll
      for (int j = 0; j < 4; ++j)
        bfr[j] = *(const short8*)&Bs2[c][(wn4 * 64 + j * 16 + l15) * 64 + cgs];
      __builtin_amdgcn_s_setprio(1);
#pragma unroll
      for (int i = 0; i < 8; ++i)
#pragma unroll
        for (int j = 0; j < 4; ++j)
          acc[i][j] = __builtin_amdgcn_mfma_f32_16x16x32_bf16(af[i], bfr[j], acc[i][j], 0, 0, 0);
      __builtin_amdgcn_s_setprio(0);
    }
    asm volatile("" ::: "memory");
    __builtin_amdgcn_s_barrier();
    asm volatile("" ::: "memory");
  }

  // epilogue: row = m0 + wm2*128 + i*16 + l4*4 + r; col = n0 + wn4*64 + j*16 + l15
#pragma unroll
  for (int j = 0; j < 4; ++j) {
    const int n = n0 + wn4 * 64 + j * 16 + l15;
    const float bv = __bfloat162float(bias[n]);
#pragma unroll
    for (int i = 0; i < 8; ++i) {
#pragma unroll
      for (int r = 0; r < 4; ++r) {
        const int mrow = m0 + wm2 * 128 + i * 16 + l4 * 4 + r;
        const float v = acc[i][j][r] + bv;
        if (store_f32) ((float*)C)[(size_t)mrow * N + n] = v;
        else           ((bf16*)C)[(size_t)mrow * N + n] = __float2bfloat16(v);
      }
    }
  }
}

// ---------------- MFMA flash attention: 8 waves (512 thr), paired chunks.
// grid (64 bh, 8 pr). Waves 0-3 own chunk A = 15-pr (long), waves 4-7 own
// chunk B = pr (short); uniform 34 iters/block. ONE shared K/V LDS stream:
// group 0 stages K, group 1 stages V (2 gload_lds16/thread/iter), dbuf,
// one barrier/iter. Per wave: QBLK=32 (2 subtiles h), S^T = mfma(K,Q),
// lane-local softmax + T13 defer-max, P roundtrip (per-wave LDS, h
// sequential), O^T = mfma(Vt,P). Short group compute-gated (wave-uniform).
__global__ __launch_bounds__(512) void attn_mfma(const bf16* __restrict__ qkv,
                                                 const bf16* __restrict__ vtg,
                                                 bf16* __restrict__ sa)
{
  __shared__ alignas(16) short Ks[2][4096];   // [buf] [dchunk8][key64][8]
  __shared__ alignas(16) short Vs[2][4096];   // [buf] [kchunk8][d64][8]
  __shared__ alignas(16) short Ps[8][1152];   // per-wave [q16][key64 pad->72]
  const int tid = threadIdx.x;
  const int bh = blockIdx.x;
  const int pr = blockIdx.y;                  // 0..7
  const size_t base = (size_t)bh * 393216;    // (bh*128)*3072
  const int w = tid >> 6;                     // 0..7
  const int g = w >> 2;                       // 0 = chunk A (long), 1 = chunk B
  const int wl = w & 3;
  const int lane = tid & 63;
  const int l15 = lane & 15, l4 = lane >> 4;
  const unsigned short* qk = (const unsigned short*)qkv;
  const unsigned short* vtb = (const unsigned short*)vtg + (size_t)bh * 131072;  // 64*2048
  short* psw = &Ps[w][0];

  const int qc = g ? pr : (15 - pr);          // this wave-group's chunk
  const int my_ktmax  = 2 * qc + 1;
  const int blk_ktmax = 2 * (15 - pr) + 1;    // union range (= A's)

  // staging source (wave-group picks its tensor): group 0 -> K, group 1 -> V.
  // per kt step: K advances 12288 (4 rows), V advances 64 (keys).
  const unsigned short* gsrc0 =
      g ? (vtb + (size_t)lane * 2048)
        : (qk + base + (size_t)(lane >> 4) * 3072 + (lane & 15) * 192 + 64);
  const size_t gstep = g ? 64 : 12288;

  // Q frags: B[n=q(16h+l15)][k=d(32kk+8l4+j)]; sa row u = qc*8+2wl+h, r=l15
  short8 qf[2][2];
#pragma unroll
  for (int h = 0; h < 2; ++h) {
    const unsigned short* pq =
        qk + base + (size_t)(qc * 8 + 2 * wl + h) * 3072 + l15 * 192 + l4 * 8;
    qf[h][0] = *(const short8*)pq;
    qf[h][1] = *(const short8*)(pq + 32);
  }

  f32x4 o[2][4] = {};                 // O^T: col=q(l15), row=d(16jn+4l4+r)
  float ml[2] = {-__builtin_inff(), -__builtin_inff()};
  float ls[2] = {0.f, 0.f};
  int cur = 0;

  // prologue: stage kt=0 into buf 0 (each thread: 2 gloads of its tensor)
  {
    short* dstbuf = g ? &Vs[0][0] : &Ks[0][0];
    gload_lds16(gsrc0 + wl * 8, dstbuf + wl * 512);
    gload_lds16(gsrc0 + (wl + 4) * 8, dstbuf + (wl + 4) * 512);
  }
  __syncthreads();

  for (int kt = 0; kt <= blk_ktmax; ++kt) {
    // stage kt+1 into the other buffer (flies under this iter's compute)
    if (kt < blk_ktmax) {
      short* dstbuf = g ? &Vs[cur ^ 1][0] : &Ks[cur ^ 1][0];
      const unsigned short* s = gsrc0 + (size_t)(kt + 1) * gstep;
      gload_lds16(s + wl * 8, dstbuf + wl * 512);
      gload_lds16(s + (wl + 4) * 8, dstbuf + (wl + 4) * 512);
    }

    if (kt <= my_ktmax) {   // wave-uniform gate (short group idles at tail)
      // ---- S^T = K . Q^T per q-subtile h: col=q(l15), row=key(16t+4l4+r)
      f32x4 sc[2][4];
#pragma unroll
      for (int t = 0; t < 4; ++t) {
        const short8 kf0 = *(const short8*)&Ks[cur][(l4) * 512 + (16 * t + l15) * 8];
        const short8 kf1 = *(const short8*)&Ks[cur][(4 + l4) * 512 + (16 * t + l15) * 8];
#pragma unroll
        for (int h = 0; h < 2; ++h) {
          f32x4 c = {};
          c = __builtin_amdgcn_mfma_f32_16x16x32_bf16(kf0, qf[h][0], c, 0, 0, 0);
          c = __builtin_amdgcn_mfma_f32_16x16x32_bf16(kf1, qf[h][1], c, 0, 0, 0);
          sc[h][t] = c;
        }
      }

      // ---- causal mask on the (at most 2) diagonal iterations
      if (kt >= 2 * qc) {
        const int kb = 64 * (kt - 2 * qc);
#pragma unroll
        for (int h = 0; h < 2; ++h) {
          const int thr = 32 * wl + 16 * h + l15;
#pragma unroll
          for (int t = 0; t < 4; ++t)
#pragma unroll
            for (int r = 0; r < 4; ++r)
              if (kb + 16 * t + 4 * l4 + r > thr) sc[h][t][r] = -__builtin_inff();
        }
      }

      // ---- lane-local online softmax per h + T13 defer-max (THR=8)
      unsigned int pk2[2][4][2];
#pragma unroll
      for (int h = 0; h < 2; ++h) {
        float mx = -__builtin_inff();
#pragma unroll
        for (int t = 0; t < 4; ++t)
#pragma unroll
          for (int r = 0; r < 4; ++r) mx = fmaxf(mx, sc[h][t][r]);
        mx = fmaxf(mx, __shfl_xor(mx, 16, 64));
        mx = fmaxf(mx, __shfl_xor(mx, 32, 64));
        if (!__all(mx <= ml[h] + 8.f)) {   // wave-uniform rescale branch
          const float m_new = fmaxf(ml[h], mx);
          const float alpha = __builtin_amdgcn_exp2f(ml[h] - m_new);
          ml[h] = m_new;
          ls[h] *= alpha;
#pragma unroll
          for (int jn = 0; jn < 4; ++jn)
#pragma unroll
            for (int r = 0; r < 4; ++r) o[h][jn][r] *= alpha;
        }
        const float m_new = ml[h];
        float s = 0.f;
#pragma unroll
        for (int t = 0; t < 4; ++t) {
          float p0 = __builtin_amdgcn_exp2f(sc[h][t][0] - m_new);
          float p1 = __builtin_amdgcn_exp2f(sc[h][t][1] - m_new);
          float p2 = __builtin_amdgcn_exp2f(sc[h][t][2] - m_new);
          float p3 = __builtin_amdgcn_exp2f(sc[h][t][3] - m_new);
          s += (p0 + p1) + (p2 + p3);
          pk2[h][t][0] = pack2bf(p0, p1);
          pk2[h][t][1] = pack2bf(p2, p3);
        }
        s += __shfl_xor(s, 16, 64);
        s += __shfl_xor(s, 32, 64);
        ls[h] += s;
      }

      // ---- P roundtrip through per-wave LDS: h sequential (program order)
      short8 pf[2][2];
#pragma unroll
      for (int h = 0; h < 2; ++h) {
#pragma unroll
        for (int t = 0; t < 4; ++t) {
          uint2 wv; wv.x = pk2[h][t][0]; wv.y = pk2[h][t][1];
          *(uint2*)(psw + l15 * 72 + 16 * t + 4 * l4) = wv;
        }
        pf[h][0] = *(const short8*)(psw + l15 * 72 + 8 * l4);
        pf[h][1] = *(const short8*)(psw + l15 * 72 + 32 + 8 * l4);
      }

      // ---- O^T += V^T . P^T : A[m=d(16jn+l15)][k=key(32ks+8l4+j)] from Vs
#pragma unroll
      for (int jn = 0; jn < 4; ++jn)
#pragma unroll
        for (int ks = 0; ks < 2; ++ks) {
          const short8 vf =
              *(const short8*)&Vs[cur][(4 * ks + l4) * 512 + (16 * jn + l15) * 8];
#pragma unroll
          for (int h = 0; h < 2; ++h)
            o[h][jn] = __builtin_amdgcn_mfma_f32_16x16x32_bf16(vf, pf[h][ks], o[h][jn], 0, 0, 0);
        }
    }

    __syncthreads();   // staged kt+1 ready (vmcnt drain); buf reads done
    cur ^= 1;
  }

  // ---- epilogue: q row u = qc*8+2wl+h, r=l15; col = 64*l15 + 16jn+4l4+r
#pragma unroll
  for (int h = 0; h < 2; ++h) {
    const float inv = 1.0f / ls[h];
    unsigned short* so =
        (unsigned short*)sa + (size_t)(bh * 128 + qc * 8 + 2 * wl + h) * 1024;
#pragma unroll
    for (int jn = 0; jn < 4; ++jn) {
      uint2 wv;
      wv.x = pack2bf(o[h][jn][0] * inv, o[h][jn][1] * inv);
      wv.y = pack2bf(o[h][jn][2] * inv, o[h][jn][3] * inv);
      *(uint2*)(so + l15 * 64 + jn * 16 + l4 * 4) = wv;
    }
  }
}

extern "C" void kernel_launch(void* const* d_in, const int* in_sizes, int n_in,
                              void* d_out, int out_size, void* d_ws, size_t ws_size,
                              hipStream_t stream)
{
  const void* x_raw    = d_in[0];  // [4,2048,1024]
  const void* Wqkv_raw = d_in[1];  // [1024,3072]
  const void* bqkv_raw = d_in[2];  // [3072]
  const void* Wout_raw = d_in[3];  // [1024,1024]
  const void* bout_raw = d_in[4];  // [1024]

  char* ws = (char*)d_ws;
  int*  flag   = (int*)ws;                                  //   256 B
  bf16* xb     = (bf16*)(ws + 256);                         //  16 MiB (8192*1024)
  bf16* wqkvT  = xb + (size_t)8192 * 1024;                  //   6 MiB (3072*1024, [N][K])
  bf16* bqkvb  = wqkvT + (size_t)3072 * 1024;               //   6 KiB
  bf16* woutT  = bqkvb + 4096;                              //   2 MiB (1024*1024, [N][K])
  bf16* boutb  = woutT + (size_t)1024 * 1024;               //   2 KiB
  bf16* qkv    = boutb + 4096;                              //  48 MiB (8192*3072)
  bf16* sa     = qkv + (size_t)8192 * 3072;                 //  16 MiB (8192*1024)
  bf16* vtg    = sa + (size_t)8192 * 1024;                  //  16 MiB (64*64*2048)

  detect_kernel<<<1, 64, 0, stream>>>((const unsigned int*)x_raw, flag);

  convert_kernel<<<(8192 * 1024 / 8 + 255) / 256, 256, 0, stream>>>(x_raw, xb, 8192 * 1024 / 8, flag);
  convert_bias_qkv<<<12, 256, 0, stream>>>(bqkv_raw, bqkvb, flag);
  convert_kernel<<<1, 256, 0, stream>>>(bout_raw, boutb, 1024 / 8, flag);
  transpose_bf16<<<dim3(3072 / 32, 1024 / 32), 256, 0, stream>>>(Wqkv_raw, wqkvT, 1024, 3072, flag, 1);
  transpose_bf16<<<dim3(1024 / 32, 1024 / 32), 256, 0, stream>>>(Wout_raw, woutT, 1024, 1024, flag, 0);

  // 1) qkv = x @ W_qkv + b_qkv   (M=8192, N=3072, K=1024); Q cols pre-scaled
  gemm256<<<dim3(3072 / 256, 8192 / 256), 512, 0, stream>>>(
      xb, wqkvT, bqkvb, qkv, 8192, 3072, 1024, 0, flag);
  // 1b) V pre-transpose: Vtg[bh][d][key]
  transpose_v<<<dim3(64, 32), 256, 0, stream>>>(qkv, vtg);
  // 2) MFMA flash attention: 8-wave paired-chunk blocks (grid 64x8, 512 thr)
  attn_mfma<<<dim3(64, 8), 512, 0, stream>>>(qkv, vtg, sa);
  // 3) out = sa @ W_out + b_out  (M=8192, N=1024, K=1024)
  gemm256<<<dim3(1024 / 256, 8192 / 256), 512, 0, stream>>>(
      sa, woutT, boutb, d_out, 8192, 1024, 1024, 1, flag);
}

// Round 12
// 290.104 us; speedup vs baseline: 1.0216x; 1.0216x over previous
//
#include <hip/hip_runtime.h>
#include <hip/hip_bf16.h>

using bf16 = __hip_bfloat16;

typedef __attribute__((ext_vector_type(8))) short short8;   // 8 x bf16 (4 VGPRs)
typedef __attribute__((ext_vector_type(4))) float f32x4;    // MFMA C/D

// MaskedMSA: B=4, S=2048, E=1024, HIDDEN=1024, HEADS=16
// Reference reshape mixes seq/hidden: with t=16u+r (u<128, r<16):
//   q[b,h,t,e] = qkv[b, 128h+u, 192r +   0 + e]
//   k[b,h,t,e] = qkv[b, 128h+u, 192r +  64 + e]
//   v[b,h,t,e] = qkv[b, 128h+u, 192r + 128 + e]
// Output: sa[b,h,t,e] -> out row 128h+u, col 64r+e. Causal mask on permuted t.
// Q columns of W_qkv/b_qkv are pre-scaled by scale*log2(e): exp2-domain scores.
//
// R10 attn: 8-wave paired-chunk flash attn (<85us, no longer top dispatch).
// R11 gemm256 2-phase: T2 swizzle verified (bank conflicts 6.3M->0) but
// 572 TF -- matches the documented 2-phase ceiling (m230/m233: stage+vmcnt+
// barrier dominate; T2/T5 gated on phase structure). R12: 4-phase interleave
// per K-step (m201 schedule at K-tile granularity): each phase = {ds_read
// subtile, setprio(1), 16 MFMA, setprio(0), raw s_barrier}. Staging + counted
// vmcnt(loads) + buffer-flip barriers unchanged (proven correct). gemm2 gets
// RI=4 (128x256 tile) so its grid fills all 256 CUs.

#define CEXP 0.03188127742677263f  // (2*1024)^-0.5 * log2(e)

__device__ __forceinline__ unsigned short f2bf(float v) {
  bf16 h = __float2bfloat16(v);
  return *(unsigned short*)&h;
}
__device__ __forceinline__ unsigned int pack2bf(float a, float b) {
  return (unsigned int)f2bf(a) | ((unsigned int)f2bf(b) << 16);
}

// async global->LDS, 16B per lane; LDS dest = wave-uniform base + lane*16.
__device__ __forceinline__ void gload_lds16(const void* g, void* lds) {
  __builtin_amdgcn_global_load_lds(
      (const __attribute__((address_space(1))) unsigned int*)(g),
      (__attribute__((address_space(3))) unsigned int*)(lds), 16, 0, 0);
}

// ---- dtype detect: flag=1 if fp32 I/O, flag=0 if bf16 I/O.
__global__ void detect_kernel(const unsigned int* __restrict__ x, int* __restrict__ flag) {
  unsigned int w = x[threadIdx.x];
  unsigned int e = (w >> 7) & 0xFF;
  bool inband = (e >= 96 && e <= 133);
  unsigned long long m = __ballot(inband);
  if (threadIdx.x == 0) flag[0] = (__popcll(m) >= 48) ? 0 : 1;
}

// ---- convert n8*8 elements to bf16 (copy if already bf16)
__global__ __launch_bounds__(256) void convert_kernel(
    const void* __restrict__ src, bf16* __restrict__ dst, int n8,
    const int* __restrict__ flag) {
  int i = blockIdx.x * 256 + threadIdx.x;
  if (i >= n8) return;
  uint4 outv;
  if (*flag) {
    const float4* s = (const float4*)src + (size_t)i * 2;
    float4 a = s[0], b = s[1];
    outv.x = pack2bf(a.x, a.y);
    outv.y = pack2bf(a.z, a.w);
    outv.z = pack2bf(b.x, b.y);
    outv.w = pack2bf(b.z, b.w);
  } else {
    outv = ((const uint4*)src)[i];
  }
  ((uint4*)dst)[i] = outv;
}

// ---- b_qkv convert with Q-column pre-scale (cols with (i%192)<64)
__global__ void convert_bias_qkv(const void* __restrict__ src, bf16* __restrict__ dst,
                                 const int* __restrict__ flag) {
  int i = blockIdx.x * 256 + threadIdx.x;
  if (i >= 3072) return;
  float v = (*flag) ? ((const float*)src)[i]
                    : __bfloat162float(((const bf16*)src)[i]);
  if ((i % 192) < 64) v *= CEXP;
  dst[i] = __float2bfloat16(v);
}

// ---- transpose src[R][C] -> dst[C][R] (bf16 out); qscale: scale rows n with
// (n%192)<64 by CEXP (W_qkv Q columns -> exp2 domain).
__global__ __launch_bounds__(256) void transpose_bf16(
    const void* __restrict__ src, bf16* __restrict__ dst, int R, int Cc,
    const int* __restrict__ flag, int qscale) {
  __shared__ float tile[32][33];
  const int c0 = blockIdx.x * 32, r0 = blockIdx.y * 32;
  const int tx = threadIdx.x & 31, ty = threadIdx.x >> 5;  // 32 x 8
  const bool f32 = (*flag != 0);
#pragma unroll
  for (int it = 0; it < 4; ++it) {
    int r = ty + it * 8;
    float v;
    if (f32) v = ((const float*)src)[(size_t)(r0 + r) * Cc + c0 + tx];
    else     v = __bfloat162float(((const bf16*)src)[(size_t)(r0 + r) * Cc + c0 + tx]);
    tile[r][tx] = v;
  }
  __syncthreads();
#pragma unroll
  for (int it = 0; it < 4; ++it) {
    int r = ty + it * 8;   // dst row n = c0 + r
    float vv = tile[tx][r];
    if (qscale && (((c0 + r) % 192) < 64)) vv *= CEXP;
    dst[(size_t)(c0 + r) * R + r0 + tx] = __float2bfloat16(vv);
  }
}

// ---- V pre-transpose: Vtg[bh][d][key] (d<64, key<2048) from permuted qkv.
__global__ __launch_bounds__(256) void transpose_v(const bf16* __restrict__ qkv,
                                                   bf16* __restrict__ vtg)
{
  __shared__ short tile[64][72];
  const int bh = blockIdx.x;
  const int k0 = blockIdx.y * 64;
  const unsigned short* qk = (const unsigned short*)qkv + (size_t)bh * 393216;
  const int key = threadIdx.x & 63;
  const int dv = threadIdx.x >> 6;      // 0..3 -> d-range dv*16
  const int gk = k0 + key;
  const unsigned short* src =
      qk + (size_t)(gk >> 4) * 3072 + (gk & 15) * 192 + 128 + dv * 16;
  *(short8*)&tile[key][dv * 16] = *(const short8*)src;
  *(short8*)&tile[key][dv * 16 + 8] = *(const short8*)(src + 8);
  __syncthreads();
  const int d = threadIdx.x & 63;
  const int kv = threadIdx.x >> 6;      // 0..3 -> key-range kv*16
  unsigned short* dst =
      (unsigned short*)vtg + ((size_t)bh * 64 + d) * 2048 + k0 + kv * 16;
  short8 a, b;
#pragma unroll
  for (int j = 0; j < 8; ++j) {
    a[j] = tile[kv * 16 + j][d];
    b[j] = tile[kv * 16 + 8 + j][d];
  }
  *(short8*)dst = a;
  *(short8*)(dst + 8) = b;
}

// ---------------- MFMA GEMM, (RI*32)x256 tile, BK=64, 8 waves, 4-phase.
// C[M,N] = A[M,K] @ BT[N,K]^T + bias. RI=8 -> 256x256 tile; RI=4 -> 128x256.
// LDS per buffer: A [RI*32 rows][8 cg][8 bf16] (row stride 128B, LINEAR dest);
// B [256][8][8]. Swizzle: LDS[row][cg] holds global k-group cg^(row&7),
// pre-permuted at the SOURCE; reads apply the same XOR -> 2-way free.
// K-step: issue (RI/2+4) gloads for t+1 -> counted vmcnt -> barrier ->
// 4 phases {(s,qi): ds_read 4-8 b128, setprio(1), 16(RI=8)/8(RI=4) MFMA,
// setprio(0), raw s_barrier}. vmcnt(0) only at final step.
template<int RI>
__global__ __launch_bounds__(512) void gemm256(
    const bf16* __restrict__ A, const bf16* __restrict__ BT,
    const bf16* __restrict__ bias, void* __restrict__ C,
    int M, int N, int K, int store_mode, const int* __restrict__ flag)
{
  __shared__ alignas(16) short As2[2][RI * 2048];  // [buf][row][cg][8]
  __shared__ alignas(16) short Bs2[2][16384];
  const bool store_f32 = store_mode && (*flag != 0);
  const int tid = threadIdx.x;
  const int lane = tid & 63;
  const int w = tid >> 6;
  const int l15 = lane & 15, l4 = lane >> 4;
  const int wm2 = w >> 2, wn4 = w & 3;   // wave tile: rows wm2*(RI*16), cols wn4*64

  // ---- T1: bijective XCD remap (nwg % 8 == 0 for all our grids)
  const int nwg = gridDim.x * gridDim.y;
  const int orig = blockIdx.x + gridDim.x * blockIdx.y;
  const int qn = nwg >> 3;
  const int swz = (orig & 7) * qn + (orig >> 3);
  const int bx = swz % gridDim.x, by = swz / gridDim.x;
  const int m0 = by * (RI * 32), n0 = bx * 256;

  // ---- staging: thread covers row srow(+64q), k-group (tid&7), source k
  // pre-swizzled by ^(row&7) so linear LDS + XOR reads match.
  const int srow = tid >> 3;                  // 0..63
  const int koff = ((tid & 7) ^ (srow & 7)) << 3;
  const bf16* pa = A + (size_t)(m0 + srow) * K + koff;
  const bf16* pb = BT + (size_t)(n0 + srow) * K + koff;
  const int dst0 = tid * 8;                   // short offset, round 0

  const int rsw = l15 & 7;                    // read-side XOR term

  f32x4 acc[RI][4] = {};
  const int nt = K >> 6;

  // prologue: stage step 0 -> buf 0 (RI/2 + 4 gloads/thread)
#pragma unroll
  for (int q = 0; q < RI / 2; ++q)
    gload_lds16(pa + (size_t)(q * 64) * K, &As2[0][q * 4096 + dst0]);
#pragma unroll
  for (int q = 0; q < 4; ++q)
    gload_lds16(pb + (size_t)(q * 64) * K, &Bs2[0][q * 4096 + dst0]);

  for (int t = 0; t < nt; ++t) {
    const int c = t & 1;
    if (t + 1 < nt) {
      const int nb = c ^ 1;
      const bf16* sa_ = pa + (size_t)(t + 1) * 64;
      const bf16* sb_ = pb + (size_t)(t + 1) * 64;
#pragma unroll
      for (int q = 0; q < RI / 2; ++q)
        gload_lds16(sa_ + (size_t)(q * 64) * K, &As2[nb][q * 4096 + dst0]);
#pragma unroll
      for (int q = 0; q < 4; ++q)
        gload_lds16(sb_ + (size_t)(q * 64) * K, &Bs2[nb][q * 4096 + dst0]);
      if constexpr (RI == 8)
        asm volatile("s_waitcnt vmcnt(8)" ::: "memory");  // batch t landed; t+1 in flight
      else
        asm volatile("s_waitcnt vmcnt(6)" ::: "memory");
    } else {
      asm volatile("s_waitcnt vmcnt(0)" ::: "memory");    // final batch
    }
    __builtin_amdgcn_s_barrier();   // all waves' loads for buf c landed
    asm volatile("" ::: "memory");

    // ---- 4 phases: (s,qi) = (0,0),(0,1),(1,0),(1,1); bfr reused across qi
    short8 bfr[4];
#pragma unroll
    for (int ph = 0; ph < 4; ++ph) {
      const int s = ph >> 1, qi = ph & 1;
      const int cgs = (((s << 2) | l4) ^ rsw) * 8;
      if (qi == 0) {
#pragma unroll
        for (int j = 0; j < 4; ++j)
          bfr[j] = *(const short8*)&Bs2[c][(wn4 * 64 + j * 16 + l15) * 64 + cgs];
      }
      short8 af[RI / 2];
#pragma unroll
      for (int i2 = 0; i2 < RI / 2; ++i2)
        af[i2] = *(const short8*)
            &As2[c][(wm2 * (RI * 16) + qi * (RI * 8) + i2 * 16 + l15) * 64 + cgs];
      __builtin_amdgcn_s_setprio(1);
#pragma unroll
      for (int i2 = 0; i2 < RI / 2; ++i2)
#pragma unroll
        for (int j = 0; j < 4; ++j)
          acc[qi * (RI / 2) + i2][j] =
              __builtin_amdgcn_mfma_f32_16x16x32_bf16(af[i2], bfr[j],
                                                      acc[qi * (RI / 2) + i2][j], 0, 0, 0);
      __builtin_amdgcn_s_setprio(0);
      asm volatile("" ::: "memory");
      __builtin_amdgcn_s_barrier();   // phase fence (scheduling; also final
      asm volatile("" ::: "memory");  //  read-complete fence before next stage)
    }
  }

  // epilogue: row = m0 + wm2*(RI*16) + i*16 + l4*4 + r; col = n0 + wn4*64 + j*16 + l15
#pragma unroll
  for (int j = 0; j < 4; ++j) {
    const int n = n0 + wn4 * 64 + j * 16 + l15;
    const float bv = __bfloat162float(bias[n]);
#pragma unroll
    for (int i = 0; i < RI; ++i) {
#pragma unroll
      for (int r = 0; r < 4; ++r) {
        const int mrow = m0 + wm2 * (RI * 16) + i * 16 + l4 * 4 + r;
        const float v = acc[i][j][r] + bv;
        if (store_f32) ((float*)C)[(size_t)mrow * N + n] = v;
        else           ((bf16*)C)[(size_t)mrow * N + n] = __float2bfloat16(v);
      }
    }
  }
}

// ---------------- MFMA flash attention: 8 waves (512 thr), paired chunks.
// grid (64 bh, 8 pr). Waves 0-3 own chunk A = 15-pr (long), waves 4-7 own
// chunk B = pr (short); uniform 34 iters/block. ONE shared K/V LDS stream:
// group 0 stages K, group 1 stages V (2 gload_lds16/thread/iter), dbuf,
// one barrier/iter. Per wave: QBLK=32 (2 subtiles h), S^T = mfma(K,Q),
// lane-local softmax + T13 defer-max, P roundtrip (per-wave LDS, h
// sequential), O^T = mfma(Vt,P). Short group compute-gated (wave-uniform).
__global__ __launch_bounds__(512) void attn_mfma(const bf16* __restrict__ qkv,
                                                 const bf16* __restrict__ vtg,
                                                 bf16* __restrict__ sa)
{
  __shared__ alignas(16) short Ks[2][4096];   // [buf] [dchunk8][key64][8]
  __shared__ alignas(16) short Vs[2][4096];   // [buf] [kchunk8][d64][8]
  __shared__ alignas(16) short Ps[8][1152];   // per-wave [q16][key64 pad->72]
  const int tid = threadIdx.x;
  const int bh = blockIdx.x;
  const int pr = blockIdx.y;                  // 0..7
  const size_t base = (size_t)bh * 393216;    // (bh*128)*3072
  const int w = tid >> 6;                     // 0..7
  const int g = w >> 2;                       // 0 = chunk A (long), 1 = chunk B
  const int wl = w & 3;
  const int lane = tid & 63;
  const int l15 = lane & 15, l4 = lane >> 4;
  const unsigned short* qk = (const unsigned short*)qkv;
  const unsigned short* vtb = (const unsigned short*)vtg + (size_t)bh * 131072;  // 64*2048
  short* psw = &Ps[w][0];

  const int qc = g ? pr : (15 - pr);          // this wave-group's chunk
  const int my_ktmax  = 2 * qc + 1;
  const int blk_ktmax = 2 * (15 - pr) + 1;    // union range (= A's)

  // staging source (wave-group picks its tensor): group 0 -> K, group 1 -> V.
  // per kt step: K advances 12288 (4 rows), V advances 64 (keys).
  const unsigned short* gsrc0 =
      g ? (vtb + (size_t)lane * 2048)
        : (qk + base + (size_t)(lane >> 4) * 3072 + (lane & 15) * 192 + 64);
  const size_t gstep = g ? 64 : 12288;

  // Q frags: B[n=q(16h+l15)][k=d(32kk+8l4+j)]; sa row u = qc*8+2wl+h, r=l15
  short8 qf[2][2];
#pragma unroll
  for (int h = 0; h < 2; ++h) {
    const unsigned short* pq =
        qk + base + (size_t)(qc * 8 + 2 * wl + h) * 3072 + l15 * 192 + l4 * 8;
    qf[h][0] = *(const short8*)pq;
    qf[h][1] = *(const short8*)(pq + 32);
  }

  f32x4 o[2][4] = {};                 // O^T: col=q(l15), row=d(16jn+4l4+r)
  float ml[2] = {-__builtin_inff(), -__builtin_inff()};
  float ls[2] = {0.f, 0.f};
  int cur = 0;

  // prologue: stage kt=0 into buf 0 (each thread: 2 gloads of its tensor)
  {
    short* dstbuf = g ? &Vs[0][0] : &Ks[0][0];
    gload_lds16(gsrc0 + wl * 8, dstbuf + wl * 512);
    gload_lds16(gsrc0 + (wl + 4) * 8, dstbuf + (wl + 4) * 512);
  }
  __syncthreads();

  for (int kt = 0; kt <= blk_ktmax; ++kt) {
    // stage kt+1 into the other buffer (flies under this iter's compute)
    if (kt < blk_ktmax) {
      short* dstbuf = g ? &Vs[cur ^ 1][0] : &Ks[cur ^ 1][0];
      const unsigned short* s = gsrc0 + (size_t)(kt + 1) * gstep;
      gload_lds16(s + wl * 8, dstbuf + wl * 512);
      gload_lds16(s + (wl + 4) * 8, dstbuf + (wl + 4) * 512);
    }

    if (kt <= my_ktmax) {   // wave-uniform gate (short group idles at tail)
      // ---- S^T = K . Q^T per q-subtile h: col=q(l15), row=key(16t+4l4+r)
      f32x4 sc[2][4];
#pragma unroll
      for (int t = 0; t < 4; ++t) {
        const short8 kf0 = *(const short8*)&Ks[cur][(l4) * 512 + (16 * t + l15) * 8];
        const short8 kf1 = *(const short8*)&Ks[cur][(4 + l4) * 512 + (16 * t + l15) * 8];
#pragma unroll
        for (int h = 0; h < 2; ++h) {
          f32x4 c = {};
          c = __builtin_amdgcn_mfma_f32_16x16x32_bf16(kf0, qf[h][0], c, 0, 0, 0);
          c = __builtin_amdgcn_mfma_f32_16x16x32_bf16(kf1, qf[h][1], c, 0, 0, 0);
          sc[h][t] = c;
        }
      }

      // ---- causal mask on the (at most 2) diagonal iterations
      if (kt >= 2 * qc) {
        const int kb = 64 * (kt - 2 * qc);
#pragma unroll
        for (int h = 0; h < 2; ++h) {
          const int thr = 32 * wl + 16 * h + l15;
#pragma unroll
          for (int t = 0; t < 4; ++t)
#pragma unroll
            for (int r = 0; r < 4; ++r)
              if (kb + 16 * t + 4 * l4 + r > thr) sc[h][t][r] = -__builtin_inff();
        }
      }

      // ---- lane-local online softmax per h + T13 defer-max (THR=8)
      unsigned int pk2[2][4][2];
#pragma unroll
      for (int h = 0; h < 2; ++h) {
        float mx = -__builtin_inff();
#pragma unroll
        for (int t = 0; t < 4; ++t)
#pragma unroll
          for (int r = 0; r < 4; ++r) mx = fmaxf(mx, sc[h][t][r]);
        mx = fmaxf(mx, __shfl_xor(mx, 16, 64));
        mx = fmaxf(mx, __shfl_xor(mx, 32, 64));
        if (!__all(mx <= ml[h] + 8.f)) {   // wave-uniform rescale branch
          const float m_new = fmaxf(ml[h], mx);
          const float alpha = __builtin_amdgcn_exp2f(ml[h] - m_new);
          ml[h] = m_new;
          ls[h] *= alpha;
#pragma unroll
          for (int jn = 0; jn < 4; ++jn)
#pragma unroll
            for (int r = 0; r < 4; ++r) o[h][jn][r] *= alpha;
        }
        const float m_new = ml[h];
        float s = 0.f;
#pragma unroll
        for (int t = 0; t < 4; ++t) {
          float p0 = __builtin_amdgcn_exp2f(sc[h][t][0] - m_new);
          float p1 = __builtin_amdgcn_exp2f(sc[h][t][1] - m_new);
          float p2 = __builtin_amdgcn_exp2f(sc[h][t][2] - m_new);
          float p3 = __builtin_amdgcn_exp2f(sc[h][t][3] - m_new);
          s += (p0 + p1) + (p2 + p3);
          pk2[h][t][0] = pack2bf(p0, p1);
          pk2[h][t][1] = pack2bf(p2, p3);
        }
        s += __shfl_xor(s, 16, 64);
        s += __shfl_xor(s, 32, 64);
        ls[h] += s;
      }

      // ---- P roundtrip through per-wave LDS: h sequential (program order)
      short8 pf[2][2];
#pragma unroll
      for (int h = 0; h < 2; ++h) {
#pragma unroll
        for (int t = 0; t < 4; ++t) {
          uint2 wv; wv.x = pk2[h][t][0]; wv.y = pk2[h][t][1];
          *(uint2*)(psw + l15 * 72 + 16 * t + 4 * l4) = wv;
        }
        pf[h][0] = *(const short8*)(psw + l15 * 72 + 8 * l4);
        pf[h][1] = *(const short8*)(psw + l15 * 72 + 32 + 8 * l4);
      }

      // ---- O^T += V^T . P^T : A[m=d(16jn+l15)][k=key(32ks+8l4+j)] from Vs
#pragma unroll
      for (int jn = 0; jn < 4; ++jn)
#pragma unroll
        for (int ks = 0; ks < 2; ++ks) {
          const short8 vf =
              *(const short8*)&Vs[cur][(4 * ks + l4) * 512 + (16 * jn + l15) * 8];
#pragma unroll
          for (int h = 0; h < 2; ++h)
            o[h][jn] = __builtin_amdgcn_mfma_f32_16x16x32_bf16(vf, pf[h][ks], o[h][jn], 0, 0, 0);
        }
    }

    __syncthreads();   // staged kt+1 ready (vmcnt drain); buf reads done
    cur ^= 1;
  }

  // ---- epilogue: q row u = qc*8+2wl+h, r=l15; col = 64*l15 + 16jn+4l4+r
#pragma unroll
  for (int h = 0; h < 2; ++h) {
    const float inv = 1.0f / ls[h];
    unsigned short* so =
        (unsigned short*)sa + (size_t)(bh * 128 + qc * 8 + 2 * wl + h) * 1024;
#pragma unroll
    for (int jn = 0; jn < 4; ++jn) {
      uint2 wv;
      wv.x = pack2bf(o[h][jn][0] * inv, o[h][jn][1] * inv);
      wv.y = pack2bf(o[h][jn][2] * inv, o[h][jn][3] * inv);
      *(uint2*)(so + l15 * 64 + jn * 16 + l4 * 4) = wv;
    }
  }
}

extern "C" void kernel_launch(void* const* d_in, const int* in_sizes, int n_in,
                              void* d_out, int out_size, void* d_ws, size_t ws_size,
                              hipStream_t stream)
{
  const void* x_raw    = d_in[0];  // [4,2048,1024]
  const void* Wqkv_raw = d_in[1];  // [1024,3072]
  const void* bqkv_raw = d_in[2];  // [3072]
  const void* Wout_raw = d_in[3];  // [1024,1024]
  const void* bout_raw = d_in[4];  // [1024]

  char* ws = (char*)d_ws;
  int*  flag   = (int*)ws;                                  //   256 B
  bf16* xb     = (bf16*)(ws + 256);                         //  16 MiB (8192*1024)
  bf16* wqkvT  = xb + (size_t)8192 * 1024;                  //   6 MiB (3072*1024, [N][K])
  bf16* bqkvb  = wqkvT + (size_t)3072 * 1024;               //   6 KiB
  bf16* woutT  = bqkvb + 4096;                              //   2 MiB (1024*1024, [N][K])
  bf16* boutb  = woutT + (size_t)1024 * 1024;               //   2 KiB
  bf16* qkv    = boutb + 4096;                              //  48 MiB (8192*3072)
  bf16* sa     = qkv + (size_t)8192 * 3072;                 //  16 MiB (8192*1024)
  bf16* vtg    = sa + (size_t)8192 * 1024;                  //  16 MiB (64*64*2048)

  detect_kernel<<<1, 64, 0, stream>>>((const unsigned int*)x_raw, flag);

  convert_kernel<<<(8192 * 1024 / 8 + 255) / 256, 256, 0, stream>>>(x_raw, xb, 8192 * 1024 / 8, flag);
  convert_bias_qkv<<<12, 256, 0, stream>>>(bqkv_raw, bqkvb, flag);
  convert_kernel<<<1, 256, 0, stream>>>(bout_raw, boutb, 1024 / 8, flag);
  transpose_bf16<<<dim3(3072 / 32, 1024 / 32), 256, 0, stream>>>(Wqkv_raw, wqkvT, 1024, 3072, flag, 1);
  transpose_bf16<<<dim3(1024 / 32, 1024 / 32), 256, 0, stream>>>(Wout_raw, woutT, 1024, 1024, flag, 0);

  // 1) qkv = x @ W_qkv + b_qkv   (M=8192, N=3072, K=1024); Q cols pre-scaled
  gemm256<8><<<dim3(3072 / 256, 8192 / 256), 512, 0, stream>>>(
      xb, wqkvT, bqkvb, qkv, 8192, 3072, 1024, 0, flag);
  // 1b) V pre-transpose: Vtg[bh][d][key]
  transpose_v<<<dim3(64, 32), 256, 0, stream>>>(qkv, vtg);
  // 2) MFMA flash attention: 8-wave paired-chunk blocks (grid 64x8, 512 thr)
  attn_mfma<<<dim3(64, 8), 512, 0, stream>>>(qkv, vtg, sa);
  // 3) out = sa @ W_out + b_out  (M=8192, N=1024, K=1024); 128x256 tile
  gemm256<4><<<dim3(1024 / 256, 8192 / 128), 512, 0, stream>>>(
      sa, woutT, boutb, d_out, 8192, 1024, 1024, 1, flag);
}

// Round 13
// 270.253 us; speedup vs baseline: 1.0966x; 1.0735x over previous
//
#include <hip/hip_runtime.h>
#include <hip/hip_bf16.h>

using bf16 = __hip_bfloat16;

typedef __attribute__((ext_vector_type(8))) short short8;   // 8 x bf16 (4 VGPRs)
typedef __attribute__((ext_vector_type(4))) float f32x4;    // MFMA C/D

// MaskedMSA: B=4, S=2048, E=1024, HIDDEN=1024, HEADS=16
// Reference reshape mixes seq/hidden: with t=16u+r (u<128, r<16):
//   q[b,h,t,e] = qkv[b, 128h+u, 192r +   0 + e]
//   k[b,h,t,e] = qkv[b, 128h+u, 192r +  64 + e]
//   v[b,h,t,e] = qkv[b, 128h+u, 192r + 128 + e]
// Output: sa[b,h,t,e] -> out row 128h+u, col 64r+e. Causal mask on permuted t.
// Q columns of W_qkv/b_qkv are pre-scaled by scale*log2(e): exp2-domain scores.
//
// R10 attn: 8-wave paired-chunk flash attn (<85us, no longer top dispatch).
// GEMM history: m97 128x128/BK32 = 85us (606 TF). R11 256^2/BK64 2-phase
// counted-vmcnt = 90us (1 blk/CU, no cross-block overlap). R12 4-phase graft
// = 126us (extra barriers, wrong phase content -- REVERTED).
// R13: 128x128 tile + BK=64 + R11's PROVEN 2-phase counted-vmcnt loop at
// 64KB LDS -> 2 blocks/CU: in-flight loads now overlap against the OTHER
// resident block's compute (m114 mechanism) instead of stalling everyone.
// Swizzle (verified 0 conflicts), XCD remap, setprio kept.

#define CEXP 0.03188127742677263f  // (2*1024)^-0.5 * log2(e)

__device__ __forceinline__ unsigned short f2bf(float v) {
  bf16 h = __float2bfloat16(v);
  return *(unsigned short*)&h;
}
__device__ __forceinline__ unsigned int pack2bf(float a, float b) {
  return (unsigned int)f2bf(a) | ((unsigned int)f2bf(b) << 16);
}

// async global->LDS, 16B per lane; LDS dest = wave-uniform base + lane*16.
__device__ __forceinline__ void gload_lds16(const void* g, void* lds) {
  __builtin_amdgcn_global_load_lds(
      (const __attribute__((address_space(1))) unsigned int*)(g),
      (__attribute__((address_space(3))) unsigned int*)(lds), 16, 0, 0);
}

// ---- dtype detect: flag=1 if fp32 I/O, flag=0 if bf16 I/O.
__global__ void detect_kernel(const unsigned int* __restrict__ x, int* __restrict__ flag) {
  unsigned int w = x[threadIdx.x];
  unsigned int e = (w >> 7) & 0xFF;
  bool inband = (e >= 96 && e <= 133);
  unsigned long long m = __ballot(inband);
  if (threadIdx.x == 0) flag[0] = (__popcll(m) >= 48) ? 0 : 1;
}

// ---- convert n8*8 elements to bf16 (copy if already bf16)
__global__ __launch_bounds__(256) void convert_kernel(
    const void* __restrict__ src, bf16* __restrict__ dst, int n8,
    const int* __restrict__ flag) {
  int i = blockIdx.x * 256 + threadIdx.x;
  if (i >= n8) return;
  uint4 outv;
  if (*flag) {
    const float4* s = (const float4*)src + (size_t)i * 2;
    float4 a = s[0], b = s[1];
    outv.x = pack2bf(a.x, a.y);
    outv.y = pack2bf(a.z, a.w);
    outv.z = pack2bf(b.x, b.y);
    outv.w = pack2bf(b.z, b.w);
  } else {
    outv = ((const uint4*)src)[i];
  }
  ((uint4*)dst)[i] = outv;
}

// ---- b_qkv convert with Q-column pre-scale (cols with (i%192)<64)
__global__ void convert_bias_qkv(const void* __restrict__ src, bf16* __restrict__ dst,
                                 const int* __restrict__ flag) {
  int i = blockIdx.x * 256 + threadIdx.x;
  if (i >= 3072) return;
  float v = (*flag) ? ((const float*)src)[i]
                    : __bfloat162float(((const bf16*)src)[i]);
  if ((i % 192) < 64) v *= CEXP;
  dst[i] = __float2bfloat16(v);
}

// ---- transpose src[R][C] -> dst[C][R] (bf16 out); qscale: scale rows n with
// (n%192)<64 by CEXP (W_qkv Q columns -> exp2 domain).
__global__ __launch_bounds__(256) void transpose_bf16(
    const void* __restrict__ src, bf16* __restrict__ dst, int R, int Cc,
    const int* __restrict__ flag, int qscale) {
  __shared__ float tile[32][33];
  const int c0 = blockIdx.x * 32, r0 = blockIdx.y * 32;
  const int tx = threadIdx.x & 31, ty = threadIdx.x >> 5;  // 32 x 8
  const bool f32 = (*flag != 0);
#pragma unroll
  for (int it = 0; it < 4; ++it) {
    int r = ty + it * 8;
    float v;
    if (f32) v = ((const float*)src)[(size_t)(r0 + r) * Cc + c0 + tx];
    else     v = __bfloat162float(((const bf16*)src)[(size_t)(r0 + r) * Cc + c0 + tx]);
    tile[r][tx] = v;
  }
  __syncthreads();
#pragma unroll
  for (int it = 0; it < 4; ++it) {
    int r = ty + it * 8;   // dst row n = c0 + r
    float vv = tile[tx][r];
    if (qscale && (((c0 + r) % 192) < 64)) vv *= CEXP;
    dst[(size_t)(c0 + r) * R + r0 + tx] = __float2bfloat16(vv);
  }
}

// ---- V pre-transpose: Vtg[bh][d][key] (d<64, key<2048) from permuted qkv.
__global__ __launch_bounds__(256) void transpose_v(const bf16* __restrict__ qkv,
                                                   bf16* __restrict__ vtg)
{
  __shared__ short tile[64][72];
  const int bh = blockIdx.x;
  const int k0 = blockIdx.y * 64;
  const unsigned short* qk = (const unsigned short*)qkv + (size_t)bh * 393216;
  const int key = threadIdx.x & 63;
  const int dv = threadIdx.x >> 6;      // 0..3 -> d-range dv*16
  const int gk = k0 + key;
  const unsigned short* src =
      qk + (size_t)(gk >> 4) * 3072 + (gk & 15) * 192 + 128 + dv * 16;
  *(short8*)&tile[key][dv * 16] = *(const short8*)src;
  *(short8*)&tile[key][dv * 16 + 8] = *(const short8*)(src + 8);
  __syncthreads();
  const int d = threadIdx.x & 63;
  const int kv = threadIdx.x >> 6;      // 0..3 -> key-range kv*16
  unsigned short* dst =
      (unsigned short*)vtg + ((size_t)bh * 64 + d) * 2048 + k0 + kv * 16;
  short8 a, b;
#pragma unroll
  for (int j = 0; j < 8; ++j) {
    a[j] = tile[kv * 16 + j][d];
    b[j] = tile[kv * 16 + 8 + j][d];
  }
  *(short8*)dst = a;
  *(short8*)(dst + 8) = b;
}

// ---------------- MFMA GEMM, 128x128 tile, BK=64, 4 waves, counted-vmcnt dbuf.
// C[M,N] = A[M,K] @ BT[N,K]^T + bias. M%128==0, N%128==0, K%64==0.
// LDS per buffer: [row128][cg8][8 bf16], row stride 128B, LINEAR dest
// (gload_lds requirement). Swizzle: LDS[row][cg] holds global k-group
// cg^(row&7) -- pre-permuted at the SOURCE; reads apply the same XOR ->
// 2-way free. Loop (R11-proven): stage(t+1) 8 gloads -> vmcnt(8) (batch t
// landed; t+1 IN FLIGHT across barrier) -> raw s_barrier -> 32 MFMA ->
// raw s_barrier. vmcnt(0) only at final step. 64KB LDS -> 2 blocks/CU:
// the other resident block's compute overlaps our barrier drains (m114).
__global__ __launch_bounds__(256) void gemm128(
    const bf16* __restrict__ A, const bf16* __restrict__ BT,
    const bf16* __restrict__ bias, void* __restrict__ C,
    int M, int N, int K, int store_mode, const int* __restrict__ flag)
{
  __shared__ alignas(16) short As2[2][8192];  // [buf][row][cg][8] = 16 KB each
  __shared__ alignas(16) short Bs2[2][8192];
  const bool store_f32 = store_mode && (*flag != 0);
  const int tid = threadIdx.x;
  const int lane = tid & 63;
  const int w = tid >> 6;                     // 0..3
  const int l15 = lane & 15, l4 = lane >> 4;
  const int wm2 = w >> 1, wn4 = w & 1;        // wave tile: rows wm2*64, cols wn4*64

  // ---- T1: bijective XCD remap (nwg % 8 == 0 for all our grids)
  const int nwg = gridDim.x * gridDim.y;
  const int orig = blockIdx.x + gridDim.x * blockIdx.y;
  const int qn = nwg >> 3;
  const int swz = (orig & 7) * qn + (orig >> 3);
  const int bx = swz % gridDim.x, by = swz / gridDim.x;
  const int m0 = by * 128, n0 = bx * 128;

  // ---- staging: thread covers row srow(+32q), k-group (tid&7); source k
  // pre-swizzled by ^(row&7) so linear LDS + XOR reads match (32q == 0 mod 8).
  const int srow = tid >> 3;                  // 0..31
  const int koff = ((tid & 7) ^ (srow & 7)) << 3;
  const bf16* pa = A + (size_t)(m0 + srow) * K + koff;
  const bf16* pb = BT + (size_t)(n0 + srow) * K + koff;
  const int dst0 = tid * 8;                   // short offset, round 0

  const int rsw = l15 & 7;                    // read-side XOR term

  f32x4 acc[4][4] = {};
  const int nt = K >> 6;

  // prologue: stage step 0 -> buf 0 (4 rounds A + 4 rounds B = 8 gloads)
#pragma unroll
  for (int q = 0; q < 4; ++q) {
    gload_lds16(pa + (size_t)(q * 32) * K, &As2[0][q * 2048 + dst0]);
    gload_lds16(pb + (size_t)(q * 32) * K, &Bs2[0][q * 2048 + dst0]);
  }

  for (int t = 0; t < nt; ++t) {
    const int c = t & 1;
    if (t + 1 < nt) {
      const int nb = c ^ 1;
      const bf16* sa_ = pa + (size_t)(t + 1) * 64;
      const bf16* sb_ = pb + (size_t)(t + 1) * 64;
#pragma unroll
      for (int q = 0; q < 4; ++q) {
        gload_lds16(sa_ + (size_t)(q * 32) * K, &As2[nb][q * 2048 + dst0]);
        gload_lds16(sb_ + (size_t)(q * 32) * K, &Bs2[nb][q * 2048 + dst0]);
      }
      asm volatile("s_waitcnt vmcnt(8)" ::: "memory");  // batch t landed; t+1 in flight
    } else {
      asm volatile("s_waitcnt vmcnt(0)" ::: "memory");  // final batch
    }
    __builtin_amdgcn_s_barrier();   // all waves' loads for buf c landed
    asm volatile("" ::: "memory");

#pragma unroll
    for (int s = 0; s < 2; ++s) {               // k-subtile of 32 within BK=64
      const int cgs = (((s << 2) | l4) ^ rsw) * 8;
      short8 af[4], bfr[4];
#pragma unroll
      for (int i = 0; i < 4; ++i)
        af[i] = *(const short8*)&As2[c][(wm2 * 64 + i * 16 + l15) * 64 + cgs];
#pragma unroll
      for (int j = 0; j < 4; ++j)
        bfr[j] = *(const short8*)&Bs2[c][(wn4 * 64 + j * 16 + l15) * 64 + cgs];
      __builtin_amdgcn_s_setprio(1);
#pragma unroll
      for (int i = 0; i < 4; ++i)
#pragma unroll
        for (int j = 0; j < 4; ++j)
          acc[i][j] = __builtin_amdgcn_mfma_f32_16x16x32_bf16(af[i], bfr[j], acc[i][j], 0, 0, 0);
      __builtin_amdgcn_s_setprio(0);
    }
    asm volatile("" ::: "memory");
    __builtin_amdgcn_s_barrier();   // reads of buf c done before next stage into c
    asm volatile("" ::: "memory");
  }

  // epilogue: row = m0 + wm2*64 + i*16 + l4*4 + r; col = n0 + wn4*64 + j*16 + l15
#pragma unroll
  for (int j = 0; j < 4; ++j) {
    const int n = n0 + wn4 * 64 + j * 16 + l15;
    const float bv = __bfloat162float(bias[n]);
#pragma unroll
    for (int i = 0; i < 4; ++i) {
#pragma unroll
      for (int r = 0; r < 4; ++r) {
        const int mrow = m0 + wm2 * 64 + i * 16 + l4 * 4 + r;
        const float v = acc[i][j][r] + bv;
        if (store_f32) ((float*)C)[(size_t)mrow * N + n] = v;
        else           ((bf16*)C)[(size_t)mrow * N + n] = __float2bfloat16(v);
      }
    }
  }
}

// ---------------- MFMA flash attention: 8 waves (512 thr), paired chunks.
// grid (64 bh, 8 pr). Waves 0-3 own chunk A = 15-pr (long), waves 4-7 own
// chunk B = pr (short); uniform 34 iters/block. ONE shared K/V LDS stream:
// group 0 stages K, group 1 stages V (2 gload_lds16/thread/iter), dbuf,
// one barrier/iter. Per wave: QBLK=32 (2 subtiles h), S^T = mfma(K,Q),
// lane-local softmax + T13 defer-max, P roundtrip (per-wave LDS, h
// sequential), O^T = mfma(Vt,P). Short group compute-gated (wave-uniform).
__global__ __launch_bounds__(512) void attn_mfma(const bf16* __restrict__ qkv,
                                                 const bf16* __restrict__ vtg,
                                                 bf16* __restrict__ sa)
{
  __shared__ alignas(16) short Ks[2][4096];   // [buf] [dchunk8][key64][8]
  __shared__ alignas(16) short Vs[2][4096];   // [buf] [kchunk8][d64][8]
  __shared__ alignas(16) short Ps[8][1152];   // per-wave [q16][key64 pad->72]
  const int tid = threadIdx.x;
  const int bh = blockIdx.x;
  const int pr = blockIdx.y;                  // 0..7
  const size_t base = (size_t)bh * 393216;    // (bh*128)*3072
  const int w = tid >> 6;                     // 0..7
  const int g = w >> 2;                       // 0 = chunk A (long), 1 = chunk B
  const int wl = w & 3;
  const int lane = tid & 63;
  const int l15 = lane & 15, l4 = lane >> 4;
  const unsigned short* qk = (const unsigned short*)qkv;
  const unsigned short* vtb = (const unsigned short*)vtg + (size_t)bh * 131072;  // 64*2048
  short* psw = &Ps[w][0];

  const int qc = g ? pr : (15 - pr);          // this wave-group's chunk
  const int my_ktmax  = 2 * qc + 1;
  const int blk_ktmax = 2 * (15 - pr) + 1;    // union range (= A's)

  // staging source (wave-group picks its tensor): group 0 -> K, group 1 -> V.
  // per kt step: K advances 12288 (4 rows), V advances 64 (keys).
  const unsigned short* gsrc0 =
      g ? (vtb + (size_t)lane * 2048)
        : (qk + base + (size_t)(lane >> 4) * 3072 + (lane & 15) * 192 + 64);
  const size_t gstep = g ? 64 : 12288;

  // Q frags: B[n=q(16h+l15)][k=d(32kk+8l4+j)]; sa row u = qc*8+2wl+h, r=l15
  short8 qf[2][2];
#pragma unroll
  for (int h = 0; h < 2; ++h) {
    const unsigned short* pq =
        qk + base + (size_t)(qc * 8 + 2 * wl + h) * 3072 + l15 * 192 + l4 * 8;
    qf[h][0] = *(const short8*)pq;
    qf[h][1] = *(const short8*)(pq + 32);
  }

  f32x4 o[2][4] = {};                 // O^T: col=q(l15), row=d(16jn+4l4+r)
  float ml[2] = {-__builtin_inff(), -__builtin_inff()};
  float ls[2] = {0.f, 0.f};
  int cur = 0;

  // prologue: stage kt=0 into buf 0 (each thread: 2 gloads of its tensor)
  {
    short* dstbuf = g ? &Vs[0][0] : &Ks[0][0];
    gload_lds16(gsrc0 + wl * 8, dstbuf + wl * 512);
    gload_lds16(gsrc0 + (wl + 4) * 8, dstbuf + (wl + 4) * 512);
  }
  __syncthreads();

  for (int kt = 0; kt <= blk_ktmax; ++kt) {
    // stage kt+1 into the other buffer (flies under this iter's compute)
    if (kt < blk_ktmax) {
      short* dstbuf = g ? &Vs[cur ^ 1][0] : &Ks[cur ^ 1][0];
      const unsigned short* s = gsrc0 + (size_t)(kt + 1) * gstep;
      gload_lds16(s + wl * 8, dstbuf + wl * 512);
      gload_lds16(s + (wl + 4) * 8, dstbuf + (wl + 4) * 512);
    }

    if (kt <= my_ktmax) {   // wave-uniform gate (short group idles at tail)
      // ---- S^T = K . Q^T per q-subtile h: col=q(l15), row=key(16t+4l4+r)
      f32x4 sc[2][4];
#pragma unroll
      for (int t = 0; t < 4; ++t) {
        const short8 kf0 = *(const short8*)&Ks[cur][(l4) * 512 + (16 * t + l15) * 8];
        const short8 kf1 = *(const short8*)&Ks[cur][(4 + l4) * 512 + (16 * t + l15) * 8];
#pragma unroll
        for (int h = 0; h < 2; ++h) {
          f32x4 c = {};
          c = __builtin_amdgcn_mfma_f32_16x16x32_bf16(kf0, qf[h][0], c, 0, 0, 0);
          c = __builtin_amdgcn_mfma_f32_16x16x32_bf16(kf1, qf[h][1], c, 0, 0, 0);
          sc[h][t] = c;
        }
      }

      // ---- causal mask on the (at most 2) diagonal iterations
      if (kt >= 2 * qc) {
        const int kb = 64 * (kt - 2 * qc);
#pragma unroll
        for (int h = 0; h < 2; ++h) {
          const int thr = 32 * wl + 16 * h + l15;
#pragma unroll
          for (int t = 0; t < 4; ++t)
#pragma unroll
            for (int r = 0; r < 4; ++r)
              if (kb + 16 * t + 4 * l4 + r > thr) sc[h][t][r] = -__builtin_inff();
        }
      }

      // ---- lane-local online softmax per h + T13 defer-max (THR=8)
      unsigned int pk2[2][4][2];
#pragma unroll
      for (int h = 0; h < 2; ++h) {
        float mx = -__builtin_inff();
#pragma unroll
        for (int t = 0; t < 4; ++t)
#pragma unroll
          for (int r = 0; r < 4; ++r) mx = fmaxf(mx, sc[h][t][r]);
        mx = fmaxf(mx, __shfl_xor(mx, 16, 64));
        mx = fmaxf(mx, __shfl_xor(mx, 32, 64));
        if (!__all(mx <= ml[h] + 8.f)) {   // wave-uniform rescale branch
          const float m_new = fmaxf(ml[h], mx);
          const float alpha = __builtin_amdgcn_exp2f(ml[h] - m_new);
          ml[h] = m_new;
          ls[h] *= alpha;
#pragma unroll
          for (int jn = 0; jn < 4; ++jn)
#pragma unroll
            for (int r = 0; r < 4; ++r) o[h][jn][r] *= alpha;
        }
        const float m_new = ml[h];
        float s = 0.f;
#pragma unroll
        for (int t = 0; t < 4; ++t) {
          float p0 = __builtin_amdgcn_exp2f(sc[h][t][0] - m_new);
          float p1 = __builtin_amdgcn_exp2f(sc[h][t][1] - m_new);
          float p2 = __builtin_amdgcn_exp2f(sc[h][t][2] - m_new);
          float p3 = __builtin_amdgcn_exp2f(sc[h][t][3] - m_new);
          s += (p0 + p1) + (p2 + p3);
          pk2[h][t][0] = pack2bf(p0, p1);
          pk2[h][t][1] = pack2bf(p2, p3);
        }
        s += __shfl_xor(s, 16, 64);
        s += __shfl_xor(s, 32, 64);
        ls[h] += s;
      }

      // ---- P roundtrip through per-wave LDS: h sequential (program order)
      short8 pf[2][2];
#pragma unroll
      for (int h = 0; h < 2; ++h) {
#pragma unroll
        for (int t = 0; t < 4; ++t) {
          uint2 wv; wv.x = pk2[h][t][0]; wv.y = pk2[h][t][1];
          *(uint2*)(psw + l15 * 72 + 16 * t + 4 * l4) = wv;
        }
        pf[h][0] = *(const short8*)(psw + l15 * 72 + 8 * l4);
        pf[h][1] = *(const short8*)(psw + l15 * 72 + 32 + 8 * l4);
      }

      // ---- O^T += V^T . P^T : A[m=d(16jn+l15)][k=key(32ks+8l4+j)] from Vs
#pragma unroll
      for (int jn = 0; jn < 4; ++jn)
#pragma unroll
        for (int ks = 0; ks < 2; ++ks) {
          const short8 vf =
              *(const short8*)&Vs[cur][(4 * ks + l4) * 512 + (16 * jn + l15) * 8];
#pragma unroll
          for (int h = 0; h < 2; ++h)
            o[h][jn] = __builtin_amdgcn_mfma_f32_16x16x32_bf16(vf, pf[h][ks], o[h][jn], 0, 0, 0);
        }
    }

    __syncthreads();   // staged kt+1 ready (vmcnt drain); buf reads done
    cur ^= 1;
  }

  // ---- epilogue: q row u = qc*8+2wl+h, r=l15; col = 64*l15 + 16jn+4l4+r
#pragma unroll
  for (int h = 0; h < 2; ++h) {
    const float inv = 1.0f / ls[h];
    unsigned short* so =
        (unsigned short*)sa + (size_t)(bh * 128 + qc * 8 + 2 * wl + h) * 1024;
#pragma unroll
    for (int jn = 0; jn < 4; ++jn) {
      uint2 wv;
      wv.x = pack2bf(o[h][jn][0] * inv, o[h][jn][1] * inv);
      wv.y = pack2bf(o[h][jn][2] * inv, o[h][jn][3] * inv);
      *(uint2*)(so + l15 * 64 + jn * 16 + l4 * 4) = wv;
    }
  }
}

extern "C" void kernel_launch(void* const* d_in, const int* in_sizes, int n_in,
                              void* d_out, int out_size, void* d_ws, size_t ws_size,
                              hipStream_t stream)
{
  const void* x_raw    = d_in[0];  // [4,2048,1024]
  const void* Wqkv_raw = d_in[1];  // [1024,3072]
  const void* bqkv_raw = d_in[2];  // [3072]
  const void* Wout_raw = d_in[3];  // [1024,1024]
  const void* bout_raw = d_in[4];  // [1024]

  char* ws = (char*)d_ws;
  int*  flag   = (int*)ws;                                  //   256 B
  bf16* xb     = (bf16*)(ws + 256);                         //  16 MiB (8192*1024)
  bf16* wqkvT  = xb + (size_t)8192 * 1024;                  //   6 MiB (3072*1024, [N][K])
  bf16* bqkvb  = wqkvT + (size_t)3072 * 1024;               //   6 KiB
  bf16* woutT  = bqkvb + 4096;                              //   2 MiB (1024*1024, [N][K])
  bf16* boutb  = woutT + (size_t)1024 * 1024;               //   2 KiB
  bf16* qkv    = boutb + 4096;                              //  48 MiB (8192*3072)
  bf16* sa     = qkv + (size_t)8192 * 3072;                 //  16 MiB (8192*1024)
  bf16* vtg    = sa + (size_t)8192 * 1024;                  //  16 MiB (64*64*2048)

  detect_kernel<<<1, 64, 0, stream>>>((const unsigned int*)x_raw, flag);

  convert_kernel<<<(8192 * 1024 / 8 + 255) / 256, 256, 0, stream>>>(x_raw, xb, 8192 * 1024 / 8, flag);
  convert_bias_qkv<<<12, 256, 0, stream>>>(bqkv_raw, bqkvb, flag);
  convert_kernel<<<1, 256, 0, stream>>>(bout_raw, boutb, 1024 / 8, flag);
  transpose_bf16<<<dim3(3072 / 32, 1024 / 32), 256, 0, stream>>>(Wqkv_raw, wqkvT, 1024, 3072, flag, 1);
  transpose_bf16<<<dim3(1024 / 32, 1024 / 32), 256, 0, stream>>>(Wout_raw, woutT, 1024, 1024, flag, 0);

  // 1) qkv = x @ W_qkv + b_qkv   (M=8192, N=3072, K=1024); Q cols pre-scaled
  gemm128<<<dim3(3072 / 128, 8192 / 128), 256, 0, stream>>>(
      xb, wqkvT, bqkvb, qkv, 8192, 3072, 1024, 0, flag);
  // 1b) V pre-transpose: Vtg[bh][d][key]
  transpose_v<<<dim3(64, 32), 256, 0, stream>>>(qkv, vtg);
  // 2) MFMA flash attention: 8-wave paired-chunk blocks (grid 64x8, 512 thr)
  attn_mfma<<<dim3(64, 8), 512, 0, stream>>>(qkv, vtg, sa);
  // 3) out = sa @ W_out + b_out  (M=8192, N=1024, K=1024)
  gemm128<<<dim3(1024 / 128, 8192 / 128), 256, 0, stream>>>(
      sa, woutT, boutb, d_out, 8192, 1024, 1024, 1, flag);
}